// Round 6
// baseline (84.948 us; speedup 1.0000x reference)
//
#include <hip/hip_runtime.h>

// QuanvolutionHybrid: 8192 x 28x28 fp32 -> 2x2 patches -> 4-qubit circuit
// (Ry encode, 2x [Ry layer + CNOT ring]) -> PauliZ feats [B,784] -> Linear(784,10)
// -> log_softmax. Fully fused, register-resident 16-amplitude simulation.
//
// R6 changes vs R5 (kernel ~9.3us; LDS pipe 5.6us was binding, HBM-x floor 4.1us):
//  * 2-row inner blocking: each lane simulates the SAME patch for two rows per
//    round -> each W ds_read_b128 reused 2x -> LDS pipe 5.6 -> 2.8us.
//    Layout: 2 groups x 32 lanes x 2 inner rows = 4 rows/wave, 16 rows/block.
//  * software-pipelined x loads: next round's 4x float2 prefetched during
//    current round's compute (covers HBM latency at 2 waves/SIMD occupancy).
//  * main loop = 6 unguarded rounds (192 patches) + 4-patch guarded tail.
// Carried: layer-0 Ry folded into encoding sincos; layer-1 tangent-form Ry with
// (prod cos)^2 deferred to one fmaf/row; W staged in LDS. wire w <-> bit (3-w).

template <int BIT>
static __device__ __forceinline__ void apply_ry_tan(float (&a)[16], float t) {
#pragma unroll
    for (int i = 0; i < 16; ++i) {
        if (i & (1 << BIT)) continue;
        float a0 = a[i];
        float a1 = a[i | (1 << BIT)];
        a[i]              = fmaf(-t, a1, a0);   // a0 - t*a1
        a[i | (1 << BIT)] = fmaf( t, a0, a1);   // a1 + t*a0
    }
}

template <int CBIT, int TBIT>
static __device__ __forceinline__ void apply_cnot(float (&a)[16]) {
#pragma unroll
    for (int i = 0; i < 16; ++i) {
        if ((i & (1 << CBIT)) && !(i & (1 << TBIT))) {
            float t = a[i];
            a[i] = a[i | (1 << TBIT)];
            a[i | (1 << TBIT)] = t;
        }
    }
}

// Simulate one patch: encoding+layer0 Ry (fused sincos) -> CNOT ring ->
// tangent-form layer1 Ry -> CNOT ring -> unnormalized PauliZ expvals z[0..3].
static __device__ __forceinline__ void sim_patch(
    float2 r0, float2 r1, const float (&h0)[4], const float (&t1w)[4], float (&z)[4])
{
    float c0, s0, c1, s1, c2, s2, c3, s3;
    __sincosf(fmaf(0.5f, r0.x, h0[0]), &s0, &c0);
    __sincosf(fmaf(0.5f, r0.y, h0[1]), &s1, &c1);
    __sincosf(fmaf(0.5f, r1.x, h0[2]), &s2, &c2);
    __sincosf(fmaf(0.5f, r1.y, h0[3]), &s3, &c3);

    float p01[4] = {c0 * c1, c0 * s1, s0 * c1, s0 * s1};
    float p23[4] = {c2 * c3, c2 * s3, s2 * c3, s2 * s3};
    float amp[16];
#pragma unroll
    for (int idx = 0; idx < 16; ++idx)
        amp[idx] = p01[idx >> 2] * p23[idx & 3];

    apply_cnot<3, 2>(amp);      // layer-0 ring (register renames, free)
    apply_cnot<2, 1>(amp);
    apply_cnot<1, 0>(amp);
    apply_cnot<0, 3>(amp);
    apply_ry_tan<3>(amp, t1w[0]);   // layer-1 Ry, scale deferred
    apply_ry_tan<2>(amp, t1w[1]);
    apply_ry_tan<1>(amp, t1w[2]);
    apply_ry_tan<0>(amp, t1w[3]);
    apply_cnot<3, 2>(amp);      // layer-1 ring (renames)
    apply_cnot<2, 1>(amp);
    apply_cnot<1, 0>(amp);
    apply_cnot<0, 3>(amp);

    float pr[16];
#pragma unroll
    for (int idx = 0; idx < 16; ++idx) pr[idx] = amp[idx] * amp[idx];

    float sp[8], dp[8];
#pragma unroll
    for (int k = 0; k < 8; ++k) {
        sp[k] = pr[2 * k] + pr[2 * k + 1];
        dp[k] = pr[2 * k] - pr[2 * k + 1];
    }
    z[3] = ((dp[0] + dp[1]) + (dp[2] + dp[3])) + ((dp[4] + dp[5]) + (dp[6] + dp[7]));
    float t[4], u[4];
#pragma unroll
    for (int k = 0; k < 4; ++k) {
        t[k] = sp[2 * k] + sp[2 * k + 1];
        u[k] = sp[2 * k] - sp[2 * k + 1];
    }
    z[2] = (u[0] + u[1]) + (u[2] + u[3]);
    z[1] = (t[0] - t[1]) + (t[2] - t[3]);
    z[0] = (t[0] + t[1]) - (t[2] + t[3]);
}

__global__ __launch_bounds__(256, 2) void quanv_fused_kernel(
    const float* __restrict__ x,       // [B,28,28]
    const float* __restrict__ params,  // [2,4]
    const float* __restrict__ W,       // [10,784]
    const float* __restrict__ bias,    // [10]
    float* __restrict__ out,           // [B,10]
    int B)
{
    __shared__ float Wl[10 * 784];     // 31360 B

    {   // cooperative W staging: 1960 float4s over 256 threads, coalesced
        const float4* Wg4 = (const float4*)W;
        float4* Wl4 = (float4*)Wl;
#pragma unroll
        for (int t = threadIdx.x; t < 1960; t += 256) Wl4[t] = Wg4[t];
    }
    __syncthreads();   // all threads reach this before any row guard

    const int lane = threadIdx.x & 63;
    const int lid  = lane & 31;                         // lane within row group
    const int wave = threadIdx.x >> 6;
    const int rowA = blockIdx.x * 16 + wave * 4 + (lane >> 5) * 2;
    if (rowA >= B) return;
    const int rowB = rowA + 1;                          // B multiple of 16 rows/block

    // Layer-0 half-angles (folded into encoding); layer-1 tangents + deferred scale.
    float h0[4], t1w[4];
    float scale2 = 1.0f;
#pragma unroll
    for (int w = 0; w < 4; ++w) {
        h0[w] = 0.5f * params[w];
        float s, c;
        __sincosf(0.5f * params[4 + w], &s, &c);
        t1w[w] = s / c;
        scale2 *= c;
    }
    scale2 *= scale2;   // (prod_w cos)^2, applied once per row after reduction

    float logitA[10], logitB[10];
#pragma unroll
    for (int c = 0; c < 10; ++c) { logitA[c] = 0.0f; logitB[c] = 0.0f; }

    const float* xA = x + (size_t)rowA * 784;
    const float* xB = x + (size_t)rowB * 784;

    // ---- software-pipelined patch loop: prefetch round k+1 during round k ----
    int p = lid;
    int i = p / 14, j = p - i * 14;
    int off = i * 56 + j * 2;
    float2 a0 = *(const float2*)(xA + off), a1 = *(const float2*)(xA + off + 28);
    float2 b0 = *(const float2*)(xB + off), b1 = *(const float2*)(xB + off + 28);

#pragma unroll 1
    for (int k = 0; k < 6; ++k) {
        // prefetch next round's patches (k=5 prefetches the tail, lid<4 only)
        const int pn = p + 32;
        float2 na0, na1, nb0, nb1;
        if (pn < 196) {
            const int ni = pn / 14, nj = pn - ni * 14;
            const int noff = ni * 56 + nj * 2;
            na0 = *(const float2*)(xA + noff); na1 = *(const float2*)(xA + noff + 28);
            nb0 = *(const float2*)(xB + noff); nb1 = *(const float2*)(xB + noff + 28);
        }

        float zA[4], zB[4];
        sim_patch(a0, a1, h0, t1w, zA);
        sim_patch(b0, b1, h0, t1w, zB);

        // One W fragment read per round, used by BOTH rows (halved LDS traffic).
        const float* wp = Wl + 4 * p;
#pragma unroll
        for (int c = 0; c < 10; ++c) {
            float4 wv = *(const float4*)(wp + c * 784);
            logitA[c] = fmaf(zA[0], wv.x, fmaf(zA[1], wv.y, fmaf(zA[2], wv.z, fmaf(zA[3], wv.w, logitA[c]))));
            logitB[c] = fmaf(zB[0], wv.x, fmaf(zB[1], wv.y, fmaf(zB[2], wv.z, fmaf(zB[3], wv.w, logitB[c]))));
        }

        p = pn;
        a0 = na0; a1 = na1; b0 = nb0; b1 = nb1;
    }

    // tail: p = lid + 192, valid for lid < 4 (data already prefetched)
    if (p < 196) {
        float zA[4], zB[4];
        sim_patch(a0, a1, h0, t1w, zA);
        sim_patch(b0, b1, h0, t1w, zB);
        const float* wp = Wl + 4 * p;
#pragma unroll
        for (int c = 0; c < 10; ++c) {
            float4 wv = *(const float4*)(wp + c * 784);
            logitA[c] = fmaf(zA[0], wv.x, fmaf(zA[1], wv.y, fmaf(zA[2], wv.z, fmaf(zA[3], wv.w, logitA[c]))));
            logitB[c] = fmaf(zB[0], wv.x, fmaf(zB[1], wv.y, fmaf(zB[2], wv.z, fmaf(zB[3], wv.w, logitB[c]))));
        }
    }

    // Butterfly reduction within each 32-lane row group (offsets < 32).
#pragma unroll
    for (int o = 16; o > 0; o >>= 1) {
#pragma unroll
        for (int c = 0; c < 10; ++c) {
            logitA[c] += __shfl_xor(logitA[c], o, 64);
            logitB[c] += __shfl_xor(logitB[c], o, 64);
        }
    }

    if (lid == 0) {   // lanes 0 and 32: write both inner rows
#pragma unroll
        for (int r = 0; r < 2; ++r) {
            const float* lg = r ? logitB : logitA;
            float v[10];
            float m = -1e30f;
#pragma unroll
            for (int c = 0; c < 10; ++c) {
                v[c] = fmaf(scale2, lg[c], bias[c]);
                m = fmaxf(m, v[c]);
            }
            float sum = 0.f;
#pragma unroll
            for (int c = 0; c < 10; ++c) sum += __expf(v[c] - m);
            float lse = m + __logf(sum);

            float2* o2 = (float2*)(out + (size_t)(rowA + r) * 10);
#pragma unroll
            for (int k = 0; k < 5; ++k)
                o2[k] = make_float2(v[2 * k] - lse, v[2 * k + 1] - lse);
        }
    }
}

extern "C" void kernel_launch(void* const* d_in, const int* in_sizes, int n_in,
                              void* d_out, int out_size, void* d_ws, size_t ws_size,
                              hipStream_t stream) {
    const float* x      = (const float*)d_in[0];
    const float* params = (const float*)d_in[1];
    const float* W      = (const float*)d_in[2];
    const float* bias   = (const float*)d_in[3];
    float* out          = (float*)d_out;

    const int B = in_sizes[0] / 784;          // 8192
    const int blocks = (B + 15) / 16;         // 16 rows/block (4 per wave)

    hipLaunchKernelGGL(quanv_fused_kernel, dim3(blocks), dim3(256), 0, stream,
                       x, params, W, bias, out, B);
}

// Round 7
// 84.947 us; speedup vs baseline: 1.0000x; 1.0000x over previous
//
#include <hip/hip_runtime.h>

// QuanvolutionHybrid: 8192 x 28x28 fp32 -> 2x2 patches -> 4-qubit circuit
// (Ry encode, 2x [Ry layer + CNOT ring]) -> PauliZ feats [B,784] -> Linear(784,10)
// -> log_softmax. Fully fused, register-resident 16-amplitude simulation.
//
// R7 = R5 layout (best measured: 83.24us) + x-prefetch pipelining only.
// R6 post-mortem: 2-row inner blocking with launch_bounds(256,2) halved
// occupancy (8 waves/CU) and regressed (+1.7us) — sincos dep chains + LDS
// latency need TLP. Here: 2 rows/wave (32-lane groups), W in LDS, occupancy
// LDS-limited at 5 blocks/CU (20 waves/CU), prefetch next round's x during
// current round's compute.
// Carried: layer-0 Ry folded into encoding sincos (Ry(p0)Ry(a)=Ry(a+p0));
// layer-1 tangent-form Ry with (prod cos)^2 deferred to one fmaf/row;
// wire w <-> bit (3-w) of the amplitude index.

template <int BIT>
static __device__ __forceinline__ void apply_ry_tan(float (&a)[16], float t) {
#pragma unroll
    for (int i = 0; i < 16; ++i) {
        if (i & (1 << BIT)) continue;
        float a0 = a[i];
        float a1 = a[i | (1 << BIT)];
        a[i]              = fmaf(-t, a1, a0);   // a0 - t*a1
        a[i | (1 << BIT)] = fmaf( t, a0, a1);   // a1 + t*a0
    }
}

template <int CBIT, int TBIT>
static __device__ __forceinline__ void apply_cnot(float (&a)[16]) {
#pragma unroll
    for (int i = 0; i < 16; ++i) {
        if ((i & (1 << CBIT)) && !(i & (1 << TBIT))) {
            float t = a[i];
            a[i] = a[i | (1 << TBIT)];
            a[i | (1 << TBIT)] = t;
        }
    }
}

// One patch: fused encode+layer0 Ry -> ring -> tangent layer1 Ry -> ring ->
// unnormalized PauliZ expvals z[0..3] (shared-scale deferred).
static __device__ __forceinline__ void sim_patch(
    float2 r0, float2 r1, const float (&h0)[4], const float (&t1w)[4], float (&z)[4])
{
    float c0, s0, c1, s1, c2, s2, c3, s3;
    __sincosf(fmaf(0.5f, r0.x, h0[0]), &s0, &c0);
    __sincosf(fmaf(0.5f, r0.y, h0[1]), &s1, &c1);
    __sincosf(fmaf(0.5f, r1.x, h0[2]), &s2, &c2);
    __sincosf(fmaf(0.5f, r1.y, h0[3]), &s3, &c3);

    float p01[4] = {c0 * c1, c0 * s1, s0 * c1, s0 * s1};
    float p23[4] = {c2 * c3, c2 * s3, s2 * c3, s2 * s3};
    float amp[16];
#pragma unroll
    for (int idx = 0; idx < 16; ++idx)
        amp[idx] = p01[idx >> 2] * p23[idx & 3];

    apply_cnot<3, 2>(amp);          // layer-0 ring (register renames, free)
    apply_cnot<2, 1>(amp);
    apply_cnot<1, 0>(amp);
    apply_cnot<0, 3>(amp);
    apply_ry_tan<3>(amp, t1w[0]);   // layer-1 Ry, scale deferred
    apply_ry_tan<2>(amp, t1w[1]);
    apply_ry_tan<1>(amp, t1w[2]);
    apply_ry_tan<0>(amp, t1w[3]);
    apply_cnot<3, 2>(amp);          // layer-1 ring (renames)
    apply_cnot<2, 1>(amp);
    apply_cnot<1, 0>(amp);
    apply_cnot<0, 3>(amp);

    float pr[16];
#pragma unroll
    for (int idx = 0; idx < 16; ++idx) pr[idx] = amp[idx] * amp[idx];

    float sp[8], dp[8];
#pragma unroll
    for (int k = 0; k < 8; ++k) {
        sp[k] = pr[2 * k] + pr[2 * k + 1];
        dp[k] = pr[2 * k] - pr[2 * k + 1];
    }
    z[3] = ((dp[0] + dp[1]) + (dp[2] + dp[3])) + ((dp[4] + dp[5]) + (dp[6] + dp[7]));
    float t[4], u[4];
#pragma unroll
    for (int k = 0; k < 4; ++k) {
        t[k] = sp[2 * k] + sp[2 * k + 1];
        u[k] = sp[2 * k] - sp[2 * k + 1];
    }
    z[2] = (u[0] + u[1]) + (u[2] + u[3]);
    z[1] = (t[0] - t[1]) + (t[2] - t[3]);
    z[0] = (t[0] + t[1]) - (t[2] + t[3]);
}

__global__ __launch_bounds__(256) void quanv_fused_kernel(
    const float* __restrict__ x,       // [B,28,28]
    const float* __restrict__ params,  // [2,4]
    const float* __restrict__ W,       // [10,784]
    const float* __restrict__ bias,    // [10]
    float* __restrict__ out,           // [B,10]
    int B)
{
    __shared__ float Wl[10 * 784];     // 31360 B; 5 blocks/CU (20 waves/CU)

    {   // cooperative W staging: 1960 float4s over 256 threads, coalesced
        const float4* Wg4 = (const float4*)W;
        float4* Wl4 = (float4*)Wl;
#pragma unroll
        for (int t = threadIdx.x; t < 1960; t += 256) Wl4[t] = Wg4[t];
    }
    __syncthreads();   // all threads reach this before any row guard

    const int lane = threadIdx.x & 63;
    const int lid  = lane & 31;                 // lane within 32-lane row group
    const int wave = threadIdx.x >> 6;
    const int row  = blockIdx.x * 8 + wave * 2 + (lane >> 5);
    if (row >= B) return;

    // Layer-0 half-angles (folded into encoding); layer-1 tangents + deferred scale.
    float h0[4], t1w[4];
    float scale2 = 1.0f;
#pragma unroll
    for (int w = 0; w < 4; ++w) {
        h0[w] = 0.5f * params[w];
        float s, c;
        __sincosf(0.5f * params[4 + w], &s, &c);
        t1w[w] = s / c;
        scale2 *= c;
    }
    scale2 *= scale2;   // (prod_w cos)^2, applied once per row after reduction

    float logit[10];
#pragma unroll
    for (int c = 0; c < 10; ++c) logit[c] = 0.0f;

    const float* xrow = x + (size_t)row * 784;

    // ---- software-pipelined patch loop: prefetch round k+1 during round k ----
    int p = lid;
    {
        // initial load for round 0
    }
    int i0 = p / 14, j0 = p - i0 * 14;
    int off = i0 * 56 + j0 * 2;
    float2 r0 = *(const float2*)(xrow + off);
    float2 r1 = *(const float2*)(xrow + off + 28);

#pragma unroll 1
    for (int k = 0; k < 6; ++k) {
        // prefetch next round's patch (k=5 prefetches the lid<4 tail)
        const int pn = p + 32;
        float2 n0, n1;
        if (pn < 196) {
            const int ni = pn / 14, nj = pn - ni * 14;
            const int noff = ni * 56 + nj * 2;
            n0 = *(const float2*)(xrow + noff);
            n1 = *(const float2*)(xrow + noff + 28);
        }

        float z[4];
        sim_patch(r0, r1, h0, t1w, z);

        const float* wp = Wl + 4 * p;    // both 32-lane groups: same addr -> broadcast
#pragma unroll
        for (int c = 0; c < 10; ++c) {
            float4 wv = *(const float4*)(wp + c * 784);
            logit[c] = fmaf(z[0], wv.x, fmaf(z[1], wv.y, fmaf(z[2], wv.z, fmaf(z[3], wv.w, logit[c]))));
        }

        p = pn;
        r0 = n0; r1 = n1;
    }

    // tail: p = lid + 192, valid for lid < 4 (data already prefetched)
    if (p < 196) {
        float z[4];
        sim_patch(r0, r1, h0, t1w, z);
        const float* wp = Wl + 4 * p;
#pragma unroll
        for (int c = 0; c < 10; ++c) {
            float4 wv = *(const float4*)(wp + c * 784);
            logit[c] = fmaf(z[0], wv.x, fmaf(z[1], wv.y, fmaf(z[2], wv.z, fmaf(z[3], wv.w, logit[c]))));
        }
    }

    // Butterfly reduction within each 32-lane row group (offsets < 32).
#pragma unroll
    for (int o = 16; o > 0; o >>= 1) {
#pragma unroll
        for (int c = 0; c < 10; ++c)
            logit[c] += __shfl_xor(logit[c], o, 64);
    }

    if (lid == 0) {   // lanes 0 and 32 hold their row's full logits
        float v[10];
        float m = -1e30f;
#pragma unroll
        for (int c = 0; c < 10; ++c) {
            v[c] = fmaf(scale2, logit[c], bias[c]);   // deferred tangent-form scale
            m = fmaxf(m, v[c]);
        }
        float sum = 0.f;
#pragma unroll
        for (int c = 0; c < 10; ++c) sum += __expf(v[c] - m);
        float lse = m + __logf(sum);

        float2* o2 = (float2*)(out + (size_t)row * 10);   // 40B rows -> 8B aligned
#pragma unroll
        for (int k = 0; k < 5; ++k)
            o2[k] = make_float2(v[2 * k] - lse, v[2 * k + 1] - lse);
    }
}

extern "C" void kernel_launch(void* const* d_in, const int* in_sizes, int n_in,
                              void* d_out, int out_size, void* d_ws, size_t ws_size,
                              hipStream_t stream) {
    const float* x      = (const float*)d_in[0];
    const float* params = (const float*)d_in[1];
    const float* W      = (const float*)d_in[2];
    const float* bias   = (const float*)d_in[3];
    float* out          = (float*)d_out;

    const int B = in_sizes[0] / 784;          // 8192
    const int blocks = (B + 7) / 8;           // 8 rows per block (2 per wave)

    hipLaunchKernelGGL(quanv_fused_kernel, dim3(blocks), dim3(256), 0, stream,
                       x, params, W, bias, out, B);
}